// Round 5
// baseline (1251.650 us; speedup 1.0000x reference)
//
#include <hip/hip_runtime.h>

#define T_DIM 200
#define U_DIM 100
#define D_DIM 512
#define V_DIM 1024
#define TU_DIM (T_DIM * U_DIM)   // 20000
#define M_TOTAL (8 * TU_DIM)     // 160000 rows
#define M_TILE 64

typedef __attribute__((ext_vector_type(8))) short bf16x8;
typedef __attribute__((ext_vector_type(4))) float f32x4;

__device__ __forceinline__ unsigned short f2bf(float f) {
    unsigned int u = __float_as_uint(f);
    u += 0x7FFFu + ((u >> 16) & 1u);   // RNE to bf16
    return (unsigned short)(u >> 16);
}

__device__ __forceinline__ float fast_tanh(float x) {
    float e = __expf(2.0f * x);
    return 1.0f - 2.0f / (e + 1.0f);
}

// ---- prep: convert joiner_w (V,D) f32 -> bf16 row-major (proven L2-resident layout) ----
__global__ void conv_w_kernel(const float* __restrict__ w, ushort4* __restrict__ wbf) {
    int i = blockIdx.x * blockDim.x + threadIdx.x;    // 131072 float4 chunks
    float4 v = reinterpret_cast<const float4*>(w)[i];
    ushort4 o;
    o.x = f2bf(v.x); o.y = f2bf(v.y); o.z = f2bf(v.z); o.w = f2bf(v.w);
    wbf[i] = o;
}

__global__ __launch_bounds__(512, 4)
void joiner_kernel(const float* __restrict__ enc,
                   const int* __restrict__ prefix,
                   const float* __restrict__ emb,
                   const unsigned short* __restrict__ wbf,
                   const float* __restrict__ bias,
                   float* __restrict__ out) {
    // A tile, XOR-swizzled: elem addr = row*512 + ((chunk ^ (row&7))*8), chunk=16B unit
    __shared__ unsigned short A_s[M_TILE * 512];     // 64 KiB -> 2 blocks/CU

    const int tid = threadIdx.x;
    const long long g0 = (long long)blockIdx.x * M_TILE;

    // ---------- Phase 1: A = bf16(tanh(enc_row + emb[prefix])), swizzled into LDS ----------
    {
        const int r = tid >> 3;          // 0..63 row
        const int q = tid & 7;
        const int g = (int)g0 + r;
        const int b = g / TU_DIM;
        const int m = g - b * TU_DIM;
        const int t = m / U_DIM;
        const int u = m - t * U_DIM;
        const float* encp = enc + (size_t)(b * T_DIM + t) * D_DIM;
        const float* embp = emb + (size_t)prefix[b * U_DIM + u] * D_DIM;
        const int r7 = r & 7;
#pragma unroll
        for (int jj = 0; jj < 8; ++jj) {
            const int d = q * 8 + jj * 64;       // elem offset (chunk = q + 8*jj)
            float4 e0 = *reinterpret_cast<const float4*>(encp + d);
            float4 e1 = *reinterpret_cast<const float4*>(encp + d + 4);
            float4 p0 = *reinterpret_cast<const float4*>(embp + d);
            float4 p1 = *reinterpret_cast<const float4*>(embp + d + 4);
            bf16x8 pk;
            pk[0] = (short)f2bf(fast_tanh(e0.x + p0.x));
            pk[1] = (short)f2bf(fast_tanh(e0.y + p0.y));
            pk[2] = (short)f2bf(fast_tanh(e0.z + p0.z));
            pk[3] = (short)f2bf(fast_tanh(e0.w + p0.w));
            pk[4] = (short)f2bf(fast_tanh(e1.x + p1.x));
            pk[5] = (short)f2bf(fast_tanh(e1.y + p1.y));
            pk[6] = (short)f2bf(fast_tanh(e1.z + p1.z));
            pk[7] = (short)f2bf(fast_tanh(e1.w + p1.w));
            const int chunk = (q + 8 * jj) ^ r7;
            *reinterpret_cast<bf16x8*>(&A_s[r * 512 + chunk * 8]) = pk;
        }
    }
    __syncthreads();   // the ONLY barrier

    // ---------- Phase 2: wave-private 64-col strips, 2 v-iterations, row-major W ----------
    const int lane = tid & 63;
    const int wid  = tid >> 6;           // 8 waves
    const int lr   = lane & 15;
    const int lg   = lane >> 4;

    for (int vt = 0; vt < 2; ++vt) {
        const int cb = vt * 512 + wid * 64;          // column base of this strip
        // b-frag [ni] slice s: W row (cb+ni*16+lr), k = s*32 + lg*8
        const unsigned short* wb = wbf + (size_t)(cb + lr) * D_DIM + lg * 8;

        f32x4 acc[4][4];
#pragma unroll
        for (int mi = 0; mi < 4; ++mi)
#pragma unroll
            for (int ni = 0; ni < 4; ++ni)
                acc[mi][ni] = (f32x4){0.f, 0.f, 0.f, 0.f};

        bf16x8 bb[2][4];                 // one-slice-ahead double buffer (static idx)
#pragma unroll
        for (int ni = 0; ni < 4; ++ni)
            bb[0][ni] = *reinterpret_cast<const bf16x8*>(wb + ni * 16 * D_DIM);

#pragma unroll
        for (int s = 0; s < 16; ++s) {
            const int cur = s & 1, nxt = cur ^ 1;
            if (s < 15) {
#pragma unroll
                for (int ni = 0; ni < 4; ++ni)
                    bb[nxt][ni] = *reinterpret_cast<const bf16x8*>(wb + ni * 16 * D_DIM + (s + 1) * 32);
            }
#pragma unroll
            for (int mi = 0; mi < 4; ++mi) {
                const int row = mi * 16 + lr;
                const int chunk = (s * 4 + lg) ^ (row & 7);
                bf16x8 af = *reinterpret_cast<const bf16x8*>(&A_s[row * 512 + chunk * 8]);
#pragma unroll
                for (int ni = 0; ni < 4; ++ni)
                    acc[mi][ni] = __builtin_amdgcn_mfma_f32_16x16x32_bf16(af, bb[cur][ni], acc[mi][ni], 0, 0, 0);
            }
        }

        // epilogue: bias + NON-TEMPORAL store (don't let output churn L2)
        float bv[4];
#pragma unroll
        for (int ni = 0; ni < 4; ++ni)
            bv[ni] = bias[cb + ni * 16 + lr];
#pragma unroll
        for (int mi = 0; mi < 4; ++mi) {
#pragma unroll
            for (int j = 0; j < 4; ++j) {
                const long long row = g0 + mi * 16 + lg * 4 + j;
                float* op = out + row * V_DIM + cb;
#pragma unroll
                for (int ni = 0; ni < 4; ++ni)
                    __builtin_nontemporal_store(acc[mi][ni][j] + bv[ni], &op[ni * 16 + lr]);
            }
        }
    }
}

extern "C" void kernel_launch(void* const* d_in, const int* in_sizes, int n_in,
                              void* d_out, int out_size, void* d_ws, size_t ws_size,
                              hipStream_t stream) {
    const float* enc    = (const float*)d_in[0];   // (8,200,512) f32
    const int*   prefix = (const int*)d_in[1];     // (8,100) int
    const float* emb    = (const float*)d_in[2];   // (1024,512) f32
    const float* jw     = (const float*)d_in[3];   // (1024,512) f32
    const float* jb     = (const float*)d_in[4];   // (1024,) f32
    float* out = (float*)d_out;                    // (8,200,100,1024) f32
    unsigned short* wbf = (unsigned short*)d_ws;   // 1 MB bf16 W, row-major

    conv_w_kernel<<<512, 256, 0, stream>>>(jw, (ushort4*)wbf);
    joiner_kernel<<<M_TOTAL / M_TILE, 512, 0, stream>>>(enc, prefix, emb, wbf, jb, out);
}

// Round 6
// 382.037 us; speedup vs baseline: 3.2763x; 3.2763x over previous
//
#include <hip/hip_runtime.h>

#define T_DIM 200
#define U_DIM 100
#define D_DIM 512
#define V_DIM 1024
#define TU_DIM (T_DIM * U_DIM)   // 20000
#define M_TOTAL (8 * TU_DIM)     // 160000 rows
#define M_TILE 64                // fallback kernel tile

typedef __attribute__((ext_vector_type(8))) short bf16x8;
typedef __attribute__((ext_vector_type(4))) float f32x4;

__device__ __forceinline__ unsigned short f2bf(float f) {
    unsigned int u = __float_as_uint(f);
    u += 0x7FFFu + ((u >> 16) & 1u);   // RNE to bf16
    return (unsigned short)(u >> 16);
}

__device__ __forceinline__ float fast_tanh(float x) {
    float e = __expf(2.0f * x);
    return 1.0f - 2.0f / (e + 1.0f);
}

// decode global row g -> (enc row ptr, emb row ptr)
__device__ __forceinline__ void row_ptrs(int g, const float* enc, const int* prefix,
                                         const float* emb, const float** encp, const float** embp) {
    const int b = g / TU_DIM;
    const int m = g - b * TU_DIM;
    const int t = m / U_DIM;
    const int u = m - t * U_DIM;
    *encp = enc + (size_t)(b * T_DIM + t) * D_DIM;
    *embp = emb + (size_t)prefix[b * U_DIM + u] * D_DIM;
}

// ---- prep: convert joiner_w (V,D) f32 -> bf16 row-major into ws[0 .. 1MB) ----
__global__ void conv_w_kernel(const float* __restrict__ w, ushort4* __restrict__ wbf) {
    int i = blockIdx.x * blockDim.x + threadIdx.x;    // 131072 float4 chunks
    float4 v = reinterpret_cast<const float4*>(w)[i];
    ushort4 o;
    o.x = f2bf(v.x); o.y = f2bf(v.y); o.z = f2bf(v.z); o.w = f2bf(v.w);
    wbf[i] = o;
}

// ---- materialize A chunk: Abf[row_local][512] = bf16(tanh(enc+emb)), rows = grid*64 ----
__global__ __launch_bounds__(512)
void mat_a_kernel(const float* __restrict__ enc, const int* __restrict__ prefix,
                  const float* __restrict__ emb, unsigned short* __restrict__ Abf, int grow0) {
    const int tid = threadIdx.x;
    const int r = tid >> 3;          // 8 threads per row
    const int q = tid & 7;
    const int rl = blockIdx.x * 64 + r;
    const float *encp, *embp;
    row_ptrs(grow0 + rl, enc, prefix, emb, &encp, &embp);
    unsigned short* ap = Abf + (size_t)rl * D_DIM;
#pragma unroll
    for (int jj = 0; jj < 8; ++jj) {
        const int d = q * 8 + jj * 64;
        float4 e0 = *reinterpret_cast<const float4*>(encp + d);
        float4 e1 = *reinterpret_cast<const float4*>(encp + d + 4);
        float4 p0 = *reinterpret_cast<const float4*>(embp + d);
        float4 p1 = *reinterpret_cast<const float4*>(embp + d + 4);
        bf16x8 pk;
        pk[0] = (short)f2bf(fast_tanh(e0.x + p0.x));
        pk[1] = (short)f2bf(fast_tanh(e0.y + p0.y));
        pk[2] = (short)f2bf(fast_tanh(e0.z + p0.z));
        pk[3] = (short)f2bf(fast_tanh(e0.w + p0.w));
        pk[4] = (short)f2bf(fast_tanh(e1.x + p1.x));
        pk[5] = (short)f2bf(fast_tanh(e1.y + p1.y));
        pk[6] = (short)f2bf(fast_tanh(e1.z + p1.z));
        pk[7] = (short)f2bf(fast_tanh(e1.w + p1.w));
        *reinterpret_cast<bf16x8*>(&ap[d]) = pk;
    }
}

#define GLOAD_LDS16(gp, lp) \
    __builtin_amdgcn_global_load_lds( \
        (const __attribute__((address_space(1))) unsigned int*)(gp), \
        (__attribute__((address_space(3))) unsigned int*)(lp), 16, 0, 0)

// ---- m97-style GEMM: C[row0+128, col0+128] = A(128xK) * W^T, K=512, BK=64, dbuf ----
__global__ __launch_bounds__(256, 2)
void gemm_kernel(const unsigned short* __restrict__ Abf, const unsigned short* __restrict__ wbf,
                 const float* __restrict__ bias, float* __restrict__ out,
                 long long grow0, int mtiles) {
    __shared__ unsigned short lds[2][2][128 * 64];   // [buf][A/W][tile] = 64 KiB

    const int tid  = threadIdx.x;
    const int lane = tid & 63;
    const int wid  = tid >> 6;                       // 4 waves: 2m x 2n
    // XCD-bijective swizzle (nwg = mtiles*8, always %8==0): contiguous logical band per XCD
    const int cpx = mtiles;                          // nwg/8
    const int logical = (blockIdx.x & 7) * cpx + (blockIdx.x >> 3);
    const int mt = logical >> 3, nt = logical & 7;
    const int row0 = mt * 128, col0 = nt * 128;
    const int wm = (wid >> 1) * 64, wn = (wid & 1) * 64;
    const int lr = lane & 15, lg = lane >> 4;

    // staging geometry: chunk c = (wid*4+i)*64 + lane; tile row = c>>3, k8 = (lane&7)*8
    const int srow  = (lane >> 3);                   // + (wid*4+i)*8
    const int kcol8 = (lane & 7) * 8;

    f32x4 acc[4][4];
#pragma unroll
    for (int mi = 0; mi < 4; ++mi)
#pragma unroll
        for (int ni = 0; ni < 4; ++ni)
            acc[mi][ni] = (f32x4){0.f, 0.f, 0.f, 0.f};

    auto stage = [&](int buf, int kt) {
        const int k0 = kt * 64;
#pragma unroll
        for (int i = 0; i < 4; ++i) {
            const unsigned short* gA =
                Abf + (size_t)(row0 + (wid * 4 + i) * 8 + srow) * D_DIM + k0 + kcol8;
            GLOAD_LDS16(gA, &lds[buf][0][(wid * 4 + i) * 512]);
        }
#pragma unroll
        for (int i = 0; i < 4; ++i) {
            const unsigned short* gW =
                wbf + (size_t)(col0 + (wid * 4 + i) * 8 + srow) * D_DIM + k0 + kcol8;
            GLOAD_LDS16(gW, &lds[buf][1][(wid * 4 + i) * 512]);
        }
    };

    auto compute = [&](int buf) {
        const unsigned short* As = &lds[buf][0][0];
        const unsigned short* Ws = &lds[buf][1][0];
#pragma unroll
        for (int kk = 0; kk < 2; ++kk) {
            bf16x8 af[4], bb[4];
#pragma unroll
            for (int mi = 0; mi < 4; ++mi)
                af[mi] = *reinterpret_cast<const bf16x8*>(&As[(wm + mi * 16 + lr) * 64 + kk * 32 + lg * 8]);
#pragma unroll
            for (int ni = 0; ni < 4; ++ni)
                bb[ni] = *reinterpret_cast<const bf16x8*>(&Ws[(wn + ni * 16 + lr) * 64 + kk * 32 + lg * 8]);
#pragma unroll
            for (int mi = 0; mi < 4; ++mi)
#pragma unroll
                for (int ni = 0; ni < 4; ++ni)
                    acc[mi][ni] = __builtin_amdgcn_mfma_f32_16x16x32_bf16(af[mi], bb[ni], acc[mi][ni], 0, 0, 0);
        }
    };

    stage(0, 0);
    __syncthreads();
#pragma unroll
    for (int kt = 0; kt < 8; ++kt) {
        if (kt < 7) stage((kt & 1) ^ 1, kt + 1);     // issue next-tile loads FIRST
        compute(kt & 1);
        __syncthreads();                             // one full-drain barrier per k-step
    }

    // epilogue: bias + store
    float bv[4];
#pragma unroll
    for (int ni = 0; ni < 4; ++ni)
        bv[ni] = bias[col0 + wn + ni * 16 + lr];
#pragma unroll
    for (int mi = 0; mi < 4; ++mi) {
#pragma unroll
        for (int j = 0; j < 4; ++j) {
            const long long row = grow0 + row0 + wm + mi * 16 + lg * 4 + j;
            float* op = out + row * V_DIM + col0 + wn;
#pragma unroll
            for (int ni = 0; ni < 4; ++ni)
                op[ni * 16 + lr] = acc[mi][ni][j] + bv[ni];
        }
    }
}

// ---- fallback (proven r3, 420 us): fused, wave-private 128-col strips ----
__global__ __launch_bounds__(512, 2)
void joiner_kernel(const float* __restrict__ enc, const int* __restrict__ prefix,
                   const float* __restrict__ emb, const unsigned short* __restrict__ wbf,
                   const float* __restrict__ bias, float* __restrict__ out) {
    __shared__ unsigned short A_s[M_TILE * 512];
    const int tid = threadIdx.x;
    const long long g0 = (long long)blockIdx.x * M_TILE;
    {
        const int r = tid >> 3, q = tid & 7;
        const float *encp, *embp;
        row_ptrs((int)g0 + r, enc, prefix, emb, &encp, &embp);
        const int r7 = r & 7;
#pragma unroll
        for (int jj = 0; jj < 8; ++jj) {
            const int d = q * 8 + jj * 64;
            float4 e0 = *reinterpret_cast<const float4*>(encp + d);
            float4 e1 = *reinterpret_cast<const float4*>(encp + d + 4);
            float4 p0 = *reinterpret_cast<const float4*>(embp + d);
            float4 p1 = *reinterpret_cast<const float4*>(embp + d + 4);
            bf16x8 pk;
            pk[0] = (short)f2bf(fast_tanh(e0.x + p0.x));
            pk[1] = (short)f2bf(fast_tanh(e0.y + p0.y));
            pk[2] = (short)f2bf(fast_tanh(e0.z + p0.z));
            pk[3] = (short)f2bf(fast_tanh(e0.w + p0.w));
            pk[4] = (short)f2bf(fast_tanh(e1.x + p1.x));
            pk[5] = (short)f2bf(fast_tanh(e1.y + p1.y));
            pk[6] = (short)f2bf(fast_tanh(e1.z + p1.z));
            pk[7] = (short)f2bf(fast_tanh(e1.w + p1.w));
            const int chunk = (q + 8 * jj) ^ r7;
            *reinterpret_cast<bf16x8*>(&A_s[r * 512 + chunk * 8]) = pk;
        }
    }
    __syncthreads();
    const int lane = tid & 63, wid = tid >> 6;
    const int wn = wid * 128, lr = lane & 15, lg = lane >> 4;
    const unsigned short* wb = wbf + (size_t)(wn + lr) * D_DIM + lg * 8;
    f32x4 acc[4][8];
#pragma unroll
    for (int mi = 0; mi < 4; ++mi)
#pragma unroll
        for (int ni = 0; ni < 8; ++ni) acc[mi][ni] = (f32x4){0.f, 0.f, 0.f, 0.f};
    bf16x8 bb[2][8];
#pragma unroll
    for (int ni = 0; ni < 8; ++ni)
        bb[0][ni] = *reinterpret_cast<const bf16x8*>(wb + ni * 16 * D_DIM);
#pragma unroll
    for (int s = 0; s < 16; ++s) {
        const int cur = s & 1, nxt = cur ^ 1;
        if (s < 15) {
#pragma unroll
            for (int ni = 0; ni < 8; ++ni)
                bb[nxt][ni] = *reinterpret_cast<const bf16x8*>(wb + ni * 16 * D_DIM + (s + 1) * 32);
        }
        bf16x8 af[4];
#pragma unroll
        for (int mi = 0; mi < 4; ++mi) {
            const int row = mi * 16 + lr;
            const int chunk = (s * 4 + lg) ^ (row & 7);
            af[mi] = *reinterpret_cast<const bf16x8*>(&A_s[row * 512 + chunk * 8]);
        }
#pragma unroll
        for (int mi = 0; mi < 4; ++mi)
#pragma unroll
            for (int ni = 0; ni < 8; ++ni)
                acc[mi][ni] = __builtin_amdgcn_mfma_f32_16x16x32_bf16(af[mi], bb[cur][ni], acc[mi][ni], 0, 0, 0);
    }
    float bv[8];
#pragma unroll
    for (int ni = 0; ni < 8; ++ni) bv[ni] = bias[wn + ni * 16 + lr];
#pragma unroll
    for (int mi = 0; mi < 4; ++mi) {
#pragma unroll
        for (int j = 0; j < 4; ++j) {
            const long long row = g0 + mi * 16 + lg * 4 + j;
            float* op = out + row * V_DIM + wn;
#pragma unroll
            for (int ni = 0; ni < 8; ++ni)
                op[ni * 16 + lr] = acc[mi][ni][j] + bv[ni];
        }
    }
}

extern "C" void kernel_launch(void* const* d_in, const int* in_sizes, int n_in,
                              void* d_out, int out_size, void* d_ws, size_t ws_size,
                              hipStream_t stream) {
    const float* enc    = (const float*)d_in[0];   // (8,200,512) f32
    const int*   prefix = (const int*)d_in[1];     // (8,100) int
    const float* emb    = (const float*)d_in[2];   // (1024,512) f32
    const float* jw     = (const float*)d_in[3];   // (1024,512) f32
    const float* jb     = (const float*)d_in[4];   // (1024,) f32
    float* out = (float*)d_out;                    // (8,200,100,1024) f32

    unsigned short* wbf = (unsigned short*)d_ws;   // ws[0..1MB): W bf16 row-major
    const size_t WB = (size_t)V_DIM * D_DIM * sizeof(unsigned short);

    conv_w_kernel<<<512, 256, 0, stream>>>(jw, (ushort4*)wbf);

    const long long avail_rows = (ws_size > WB) ? (long long)((ws_size - WB) / (D_DIM * 2)) : 0;
    long long tpc = avail_rows / 128;              // M-tiles per chunk the ws can hold
    const int tiles_total = M_TOTAL / 128;         // 1250

    if (tpc >= 125) {                              // de-fused path: materialize A + m97 GEMM
        if (tpc > tiles_total) tpc = tiles_total;
        unsigned short* Abf = wbf + (size_t)V_DIM * D_DIM;
        int done = 0;
        while (done < tiles_total) {
            const int tiles = (int)((tiles_total - done < tpc) ? (tiles_total - done) : tpc);
            const int rows = tiles * 128;
            const long long grow0 = (long long)done * 128;
            mat_a_kernel<<<rows / 64, 512, 0, stream>>>(enc, prefix, emb, Abf, (int)grow0);
            gemm_kernel<<<tiles * 8, 256, 0, stream>>>(Abf, wbf, jb, out, grow0, tiles);
            done += tiles;
        }
    } else {                                       // fused fallback (proven 420 us)
        joiner_kernel<<<M_TOTAL / M_TILE, 512, 0, stream>>>(enc, prefix, emb, wbf, jb, out);
    }
}